// Round 2
// baseline (645.524 us; speedup 1.0000x reference)
//
#include <hip/hip_runtime.h>

// GraphAttention (e3nn-style) on MI355X — Round 6: i-split across lane groups.
// Round-5 post-mortem: EPB=512 -> only 196 blocks for 256 CUs (Occupancy 8.3%,
// 1 wave/SIMD). edge_k 93us at VALUBusy 45% = latency-bound, no TLP.
// Fix: keep 2 edges/thread amortization but split the TP i-range across the
// wave's 4 lane-groups (p = lane>>4). Per-wave LDS reads drop to 1/4 sweep,
// blocks 196 -> 782 (12 waves/CU, 3/SIMD). Groups read 4 distinct 16B chunks
// per instr (group stride % 128B == 16 -> disjoint bank quads, conflict-free).
// x comes per-lane straight from global f32 (node_ft is L2-resident 1.6MB) --
// no x staging, no x bf16 rounding. Partials combine via shfl_xor(16/32).
//
// Dims: M0=16 M1=8 Q0=8 Q1=4 O0=16 O1=8 EDGE_BASIS=16 HIDDEN=32
// TPK [32][320]: w1[0,128) w2[128,192) w3[192,256) w4[256,288) w5[288,320)
// TPV [32][640]: w1[0,256) w2[256,384) w3[384,512) w4[512,576) w5[576,640)
//
// Pipeline: node_pre | count_edges | scan | edge_k | edge_v_a | edge_v_b | node_reduce
// ws (4B units): qd[N*20] | cnt[N] | start[N+1] | cursor[N] | flag | pad |
//                exbuf[E] | sabuf[E] | posbuf[E] | vbuf[E*40]

#define BS 256           // threads per block (edge kernels)
#define EPB 128          // edges per block: 4 waves x 16 q-lanes x 2 edges

__device__ __forceinline__ float silu_f(float x) {
    return x * (1.0f / (1.0f + __expf(-x)));
}
__device__ __forceinline__ unsigned short f2b(float f) {   // f32 -> bf16 (RNE)
    unsigned u = __float_as_uint(f);
    u += 0x7fffu + ((u >> 16) & 1u);
    return (unsigned short)(u >> 16);
}
__device__ __forceinline__ float bl(unsigned u) {          // low bf16 -> f32
    return __uint_as_float(u << 16);
}
__device__ __forceinline__ float bh(unsigned u) {          // high bf16 -> f32
    return __uint_as_float(u & 0xffff0000u);
}
__device__ __forceinline__ unsigned pk2(float a, float b) { // pack 2 bf16
    return (unsigned)f2b(a) | ((unsigned)f2b(b) << 16);
}
__device__ __forceinline__ void up8(const uint4 a, float* w) {
    w[0] = bl(a.x); w[1] = bh(a.x); w[2] = bl(a.y); w[3] = bh(a.y);
    w[4] = bl(a.z); w[5] = bh(a.z); w[6] = bl(a.w); w[7] = bh(a.w);
}
__device__ __forceinline__ float wred4(float v) {          // sum over 4 p-groups
    v += __shfl_xor(v, 16);
    v += __shfl_xor(v, 32);
    return v;
}

__global__ __launch_bounds__(256) void node_pre(
    const float* __restrict__ node_ft,
    const int*   __restrict__ ei,
    const float* __restrict__ w_q_s, const float* __restrict__ w_q_v,
    const float* __restrict__ wdot_s, const float* __restrict__ wdot_v,
    float* __restrict__ qd, int* __restrict__ cnt, int* __restrict__ flag,
    int N, int E)
{
    const int n = blockIdx.x * blockDim.x + threadIdx.x;
    if (n == 0) {
        int acc = 0;
        const int kmax = (E < 64) ? E : 64;
        for (int k = 0; k < kmax; ++k) acc |= ei[2*k + 1];
        *flag = (acc == 0) ? 1 : 0;   // int64 layout => odd words all zero
    }
    if (n >= N) return;
    cnt[n] = 0;

    const float* nf = node_ft + (size_t)n * 40;
    float xs[16];
#pragma unroll
    for (int i = 0; i < 16; ++i) xs[i] = nf[i];
    float q[8];
#pragma unroll
    for (int o = 0; o < 8; ++o) {
        float a = 0.f;
#pragma unroll
        for (int i = 0; i < 16; ++i) a += xs[i] * w_q_s[i*8 + o];
        q[o] = a * 0.25f;
    }
    float* qdn = qd + (size_t)n * 20;
#pragma unroll
    for (int j = 0; j < 8; ++j) {
        float a = 0.f;
#pragma unroll
        for (int i = 0; i < 8; ++i) a += q[i] * wdot_s[i*8 + j];
        qdn[j] = a;
    }
    float xv[8][3];
#pragma unroll
    for (int i = 0; i < 8; ++i)
#pragma unroll
        for (int c = 0; c < 3; ++c) xv[i][c] = nf[16 + i*3 + c];
    float qv[4][3];
#pragma unroll
    for (int o = 0; o < 4; ++o)
#pragma unroll
        for (int c = 0; c < 3; ++c) {
            float a = 0.f;
#pragma unroll
            for (int i = 0; i < 8; ++i) a += xv[i][c] * w_q_v[i*4 + o];
            qv[o][c] = a * 0.35355339059327379f;
        }
#pragma unroll
    for (int j = 0; j < 4; ++j)
#pragma unroll
        for (int c = 0; c < 3; ++c) {
            float a = 0.f;
#pragma unroll
            for (int i = 0; i < 4; ++i) a += qv[i][c] * wdot_v[i*4 + j];
            qdn[8 + j*3 + c] = a;
        }
}

__global__ __launch_bounds__(256) void count_edges(
    const int* __restrict__ ei, int* __restrict__ cnt,
    const int* __restrict__ flag, int E)
{
    const int e = blockIdx.x * blockDim.x + threadIdx.x;
    if (e >= E) return;
    const int is64 = *flag;
    const int rcv = is64 ? ei[2*(E + e)] : ei[E + e];
    atomicAdd(cnt + rcv, 1);
}

// 1 block, 1024 threads; shuffle-based scan (few barriers).
__global__ __launch_bounds__(1024) void scan_kernel(
    const int* __restrict__ cnt, int* __restrict__ start,
    int* __restrict__ cursor, int N)
{
    __shared__ int wsum[16];
    __shared__ int s_carry;
    const int tid = threadIdx.x, wave = tid >> 6, lane = tid & 63;
    if (tid == 0) s_carry = 0;
    __syncthreads();
    for (int base = 0; base < N; base += 1024) {
        const int i = base + tid;
        const int v = (i < N) ? cnt[i] : 0;
        int x = v;                                  // inclusive intra-wave scan
#pragma unroll
        for (int d = 1; d < 64; d <<= 1) {
            const int y = __shfl_up(x, d, 64);
            if (lane >= d) x += y;
        }
        if (lane == 63) wsum[wave] = x;
        __syncthreads();
        if (wave == 0 && lane < 16) {
            int w = wsum[lane];
#pragma unroll
            for (int d = 1; d < 16; d <<= 1) {
                const int y = __shfl_up(w, d, 64);
                if (lane >= d) w += y;              // lanes 16..63 inactive
            }
            wsum[lane] = w;                         // inclusive wave-prefix
        }
        __syncthreads();
        const int woff = (wave == 0) ? 0 : wsum[wave - 1];
        const int carry = s_carry;
        if (i < N) {
            const int s = carry + woff + x - v;     // exclusive
            start[i] = s;
            cursor[i] = s;
        }
        __syncthreads();
        if (tid == 0) s_carry = carry + wsum[15];
        __syncthreads();
    }
    if (tid == 0) start[N] = s_carry;
}

// ===================== edge_k: K-side TP + dot + softmax terms =====================
// LDS: 4 groups x 321 uint4 = 20544 B (group stride 5136 B; 5136%128==16 ->
// the 4 concurrent group reads land on disjoint bank quads).
// Per-group chunk map (uint4 idx): [0,128)=w1(k*32+j), [128,192)=w3(k2*32+j),
// [192,256)=w2(k*32+j), [256,320)=w4|w5 interleaved (k*32+j).
__global__ __launch_bounds__(BS) void edge_k(
    const float* __restrict__ node_ft,
    const int*   __restrict__ ei,
    const float* __restrict__ edge_sh,
    const float* __restrict__ edge_scalars,
    const float* __restrict__ fck_w1,
    const float* __restrict__ fck_w2,
    const float* __restrict__ qd,
    int*   __restrict__ cursor,
    float* __restrict__ exbuf,              // [E] CSR order
    float* __restrict__ sabuf,              // [E] edge order
    int*   __restrict__ posbuf,             // [E] edge order
    const int* __restrict__ flag,
    int N, int E)
{
    __shared__ uint4 sk4[4 * 321];          // 20544 B

    const int tid = threadIdx.x;
    // ---- stage weights (bf16, group-split, permuted) ----
    for (int idx = tid; idx < 4 * 320; idx += BS) {
        const int p = idx / 320;
        const int local = idx - p * 320;
        unsigned u0, u1, u2, u3;
        if (local < 256) {
            int j, c0;
            if (local < 128) {                       // w1: i = 4p+k, 8 cols
                const int k = local >> 5; j = local & 31; c0 = (4*p + k) * 8;
            } else if (local < 192) {                // w3: i0 = 4p+2k2, 2 i's x4
                const int l = local - 128; const int k2 = l >> 5; j = l & 31;
                c0 = 192 + (4*p + 2*k2) * 4;
            } else {                                 // w2: i = 2p+k, 8 cols
                const int l = local - 192; const int k = l >> 5; j = l & 31;
                c0 = 128 + (2*p + k) * 8;
            }
            const float* src = fck_w2 + j * 320 + c0;
            u0 = pk2(src[0], src[1]); u1 = pk2(src[2], src[3]);
            u2 = pk2(src[4], src[5]); u3 = pk2(src[6], src[7]);
        } else {                                     // w4|w5: i = 2p+k
            const int l = local - 256; const int k = l >> 5; const int j = l & 31;
            const int i = 2*p + k;
            const float* s4 = fck_w2 + j * 320 + 256 + i * 4;
            const float* s5 = fck_w2 + j * 320 + 288 + i * 4;
            u0 = pk2(s4[0], s4[1]); u1 = pk2(s4[2], s4[3]);
            u2 = pk2(s5[0], s5[1]); u3 = pk2(s5[2], s5[3]);
        }
        sk4[p * 321 + local] = make_uint4(u0, u1, u2, u3);
    }

    const int lane = tid & 63;
    const int p = lane >> 4;
    const int q = lane & 15;
    const int w = tid >> 6;
    const int e0 = blockIdx.x * EPB + w * 32 + 2 * q;
    const int e1 = e0 + 1;
    const bool val0 = (e0 < E), val1 = (e1 < E);
    const int e0c = val0 ? e0 : (E - 1);
    const int e1c = val1 ? e1 : (E - 1);

    const int is64 = *flag;
    const int snd0 = is64 ? ei[2*e0c]       : ei[e0c];
    const int rcv0 = is64 ? ei[2*(E + e0c)] : ei[E + e0c];
    const int snd1 = is64 ? ei[2*e1c]       : ei[e1c];
    const int rcv1 = is64 ? ei[2*(E + e1c)] : ei[E + e1c];

    int pos0 = 0, pos1 = 0;
    if (p == 0) {                                    // one claimant per edge
        if (val0) pos0 = atomicAdd(cursor + rcv0, 1);
        if (val1) pos1 = atomicAdd(cursor + rcv1, 1);
    }

    const float4 s40 = *(const float4*)(edge_sh + (size_t)e0c * 4);
    const float4 s41 = *(const float4*)(edge_sh + (size_t)e1c * 4);
    const float sh_s0 = s40.x, sh_s1 = s41.x;
    const float sh_v0[3] = {s40.y, s40.z, s40.w};
    const float sh_v1[3] = {s41.y, s41.z, s41.w};

    const float* nf0 = node_ft + (size_t)snd0 * 40;
    const float* nf1 = node_ft + (size_t)snd1 * 40;

    __syncthreads();                                 // weights staged; no barriers below

    // ---- hidden activations (per lane, both edges; redundant across p) ----
    float hk0[32], hk1[32];
    {
        float es[16];
        const float4* a0 = (const float4*)(edge_scalars + (size_t)e0c * 16);
#pragma unroll
        for (int t = 0; t < 4; ++t) {
            const float4 v = a0[t];
            es[4*t+0]=v.x; es[4*t+1]=v.y; es[4*t+2]=v.z; es[4*t+3]=v.w;
        }
#pragma unroll
        for (int j = 0; j < 32; ++j) {
            float a = 0.f;
#pragma unroll
            for (int t = 0; t < 16; ++t) a += es[t] * fck_w1[t*32 + j];
            hk0[j] = silu_f(a * 0.25f);
        }
        const float4* a1 = (const float4*)(edge_scalars + (size_t)e1c * 16);
#pragma unroll
        for (int t = 0; t < 4; ++t) {
            const float4 v = a1[t];
            es[4*t+0]=v.x; es[4*t+1]=v.y; es[4*t+2]=v.z; es[4*t+3]=v.w;
        }
#pragma unroll
        for (int j = 0; j < 32; ++j) {
            float a = 0.f;
#pragma unroll
            for (int t = 0; t < 16; ++t) a += es[t] * fck_w1[t*32 + j];
            hk1[j] = silu_f(a * 0.25f);
        }
    }

    const uint4* g = sk4 + p * 321;

    // ---- tk1 (xs -> scalar, this group's i = 4p+k) ----
    float K10[8] = {}, K11[8] = {};
#pragma unroll 1
    for (int k = 0; k < 4; ++k) {
        const float x0 = nf0[4*p + k];
        const float x1 = nf1[4*p + k];
        const uint4* gk = g + k * 32;
#pragma unroll
        for (int j = 0; j < 32; ++j) {
            const uint4 a = gk[j];
            const float t0 = x0 * hk0[j], t1 = x1 * hk1[j];
            float wv[8]; up8(a, wv);
#pragma unroll
            for (int o = 0; o < 8; ++o) { K10[o] += t0*wv[o]; K11[o] += t1*wv[o]; }
        }
    }

    // ---- tk3 (xs -> vec path scalar part; i0 = 4p+2k2, pairs) ----
    float K30[4] = {}, K31[4] = {};
#pragma unroll 1
    for (int k2 = 0; k2 < 2; ++k2) {
        const int i0 = 4*p + 2*k2;
        const float xa0 = nf0[i0], xb0 = nf0[i0+1];
        const float xa1 = nf1[i0], xb1 = nf1[i0+1];
        const uint4* gk = g + 128 + k2 * 32;
#pragma unroll
        for (int j = 0; j < 32; ++j) {
            const uint4 a = gk[j];
            float wv[8]; up8(a, wv);
            const float ta0 = xa0*hk0[j], tb0 = xb0*hk0[j];
            const float ta1 = xa1*hk1[j], tb1 = xb1*hk1[j];
#pragma unroll
            for (int o = 0; o < 4; ++o) {
                K30[o] += ta0*wv[o] + tb0*wv[4+o];
                K31[o] += ta1*wv[o] + tb1*wv[4+o];
            }
        }
    }

    // ---- tk2 + tk4/tk5 (vector inputs; this group's i = 2p+k) ----
    float K20[8] = {}, K21[8] = {};
    float KV0[12] = {}, KV1[12] = {};
    const float c3 = 0.57735026918962576f;
    const float c7 = 0.70710678118654752f;
#pragma unroll 1
    for (int k = 0; k < 2; ++k) {
        const int i = 2*p + k;
        const float x00 = nf0[16 + 3*i], x01 = nf0[17 + 3*i], x02 = nf0[18 + 3*i];
        const float x10 = nf1[16 + 3*i], x11 = nf1[17 + 3*i], x12 = nf1[18 + 3*i];
        const float pv0 = (x00*sh_v0[0] + x01*sh_v0[1] + x02*sh_v0[2]) * c3;
        const float pv1 = (x10*sh_v1[0] + x11*sh_v1[1] + x12*sh_v1[2]) * c3;
        float W40[4] = {}, W41[4] = {}, W50[4] = {}, W51[4] = {};
        const uint4* g2  = g + 192 + k * 32;
        const uint4* g45 = g + 256 + k * 32;
#pragma unroll
        for (int j = 0; j < 32; ++j) {
            const uint4 a = g2[j];
            const uint4 b = g45[j];
            const float t0 = pv0 * hk0[j], t1 = pv1 * hk1[j];
            float wv[8]; up8(a, wv);
#pragma unroll
            for (int o = 0; o < 8; ++o) { K20[o] += t0*wv[o]; K21[o] += t1*wv[o]; }
            float wu[8]; up8(b, wu);
            const float h0 = hk0[j], h1 = hk1[j];
#pragma unroll
            for (int o = 0; o < 4; ++o) {
                W40[o] += h0*wu[o];   W41[o] += h1*wu[o];
                W50[o] += h0*wu[4+o]; W51[o] += h1*wu[4+o];
            }
        }
        const float s00 = sh_s0*x00, s01 = sh_s0*x01, s02 = sh_s0*x02;
        const float s10 = sh_s1*x10, s11 = sh_s1*x11, s12 = sh_s1*x12;
        const float cx00 = c7*(x01*sh_v0[2] - x02*sh_v0[1]);
        const float cx01 = c7*(x02*sh_v0[0] - x00*sh_v0[2]);
        const float cx02 = c7*(x00*sh_v0[1] - x01*sh_v0[0]);
        const float cx10 = c7*(x11*sh_v1[2] - x12*sh_v1[1]);
        const float cx11 = c7*(x12*sh_v1[0] - x10*sh_v1[2]);
        const float cx12 = c7*(x10*sh_v1[1] - x11*sh_v1[0]);
#pragma unroll
        for (int o = 0; o < 4; ++o) {
            KV0[o*3+0] += s00*W40[o] + cx00*W50[o];
            KV0[o*3+1] += s01*W40[o] + cx01*W50[o];
            KV0[o*3+2] += s02*W40[o] + cx02*W50[o];
            KV1[o*3+0] += s10*W41[o] + cx10*W51[o];
            KV1[o*3+1] += s11*W41[o] + cx11*W51[o];
            KV1[o*3+2] += s12*W41[o] + cx12*W51[o];
        }
    }

    // ---- combine partials across the 4 p-groups ----
#pragma unroll
    for (int o = 0; o < 8; ++o) { K10[o] = wred4(K10[o]); K11[o] = wred4(K11[o]); }
#pragma unroll
    for (int o = 0; o < 8; ++o) { K20[o] = wred4(K20[o]); K21[o] = wred4(K21[o]); }
#pragma unroll
    for (int o = 0; o < 4; ++o) { K30[o] = wred4(K30[o]); K31[o] = wred4(K31[o]); }
#pragma unroll
    for (int o = 0; o < 12; ++o) { KV0[o] = wred4(KV0[o]); KV1[o] = wred4(KV1[o]); }

    if (p == 0) {
        float qd0[20], qd1[20];
        {
            const float4* r0p = (const float4*)(qd + (size_t)rcv0 * 20);
            const float4* r1p = (const float4*)(qd + (size_t)rcv1 * 20);
#pragma unroll
            for (int t = 0; t < 5; ++t) {
                const float4 a = r0p[t], b = r1p[t];
                qd0[4*t+0]=a.x; qd0[4*t+1]=a.y; qd0[4*t+2]=a.z; qd0[4*t+3]=a.w;
                qd1[4*t+0]=b.x; qd1[4*t+1]=b.y; qd1[4*t+2]=b.z; qd1[4*t+3]=b.w;
            }
        }
        float ds0 = 0.f, ds1 = 0.f;
#pragma unroll
        for (int o = 0; o < 8; ++o) {
            ds0 += qd0[o] * (sh_s0*K10[o] + K20[o]);
            ds1 += qd1[o] * (sh_s1*K11[o] + K21[o]);
        }
        float dv0 = 0.f, dv1 = 0.f;
#pragma unroll
        for (int o = 0; o < 4; ++o)
#pragma unroll
            for (int c = 0; c < 3; ++c) {
                dv0 += qd0[8 + o*3 + c] * (K30[o]*sh_v0[c] + KV0[o*3+c]);
                dv1 += qd1[8 + o*3 + c] * (K31[o]*sh_v1[c] + KV1[o*3+c]);
            }
        const float dot0 = ds0 * 4.0343567508008e-3f + dv0 * 2.0171788261497e-3f;
        const float dot1 = ds1 * 4.0343567508008e-3f + dv1 * 2.0171788261497e-3f;
        const float sa0 = __expf(0.5f * dot0);
        const float sa1 = __expf(0.5f * dot1);
        if (val0) { exbuf[pos0] = sa0*sa0; sabuf[e0] = sa0; posbuf[e0] = pos0; }
        if (val1) { exbuf[pos1] = sa1*sa1; sabuf[e1] = sa1; posbuf[e1] = pos1; }
    }
}

// ===================== edge_v_a: V scalar outputs (cols [0,384)) =====================
// LDS: 4 x 385 uint4 = 24640 B (stride 6160 B, %128==16 -> conflict-free).
// Chunk map: [0,256)=w1 ((k*32+j)*2+h), [256,384)=w2 (256+(k*32+j)*2+h).
// shs folded into xs (f32, in registers) -> only W is bf16-rounded.
__global__ __launch_bounds__(BS) void edge_v_a(
    const float* __restrict__ node_ft,
    const int*   __restrict__ ei,
    const float* __restrict__ edge_sh,
    const float* __restrict__ edge_scalars,
    const float* __restrict__ fcv_w1,
    const float* __restrict__ fcv_w2,
    const float* __restrict__ sabuf,
    const int*   __restrict__ posbuf,
    float* __restrict__ vbuf,               // [E,40]
    const int* __restrict__ flag,
    int E)
{
    __shared__ uint4 sa4[4 * 385];          // 24640 B

    const int tid = threadIdx.x;
    for (int idx = tid; idx < 4 * 384; idx += BS) {
        const int p = idx / 384;
        const int local = idx - p * 384;
        int j, c0;
        if (local < 256) {                           // w1: i = 4p+k, 16 cols in 2 halves
            const int k = local >> 6; j = (local >> 1) & 31; const int h = local & 1;
            c0 = (4*p + k) * 16 + 8*h;
        } else {                                     // w2: i = 2p+k
            const int l = local - 256;
            const int k = l >> 6; j = (l >> 1) & 31; const int h = l & 1;
            c0 = 256 + (2*p + k) * 16 + 8*h;
        }
        const float* src = fcv_w2 + j * 640 + c0;
        sa4[p * 385 + local] = make_uint4(
            pk2(src[0], src[1]), pk2(src[2], src[3]),
            pk2(src[4], src[5]), pk2(src[6], src[7]));
    }

    const int lane = tid & 63;
    const int p = lane >> 4;
    const int q = lane & 15;
    const int w = tid >> 6;
    const int e0 = blockIdx.x * EPB + w * 32 + 2 * q;
    const int e1 = e0 + 1;
    const bool val0 = (e0 < E), val1 = (e1 < E);
    const int e0c = val0 ? e0 : (E - 1);
    const int e1c = val1 ? e1 : (E - 1);

    const int is64 = *flag;
    const int snd0 = is64 ? ei[2*e0c] : ei[e0c];
    const int snd1 = is64 ? ei[2*e1c] : ei[e1c];

    const float4 s40 = *(const float4*)(edge_sh + (size_t)e0c * 4);
    const float4 s41 = *(const float4*)(edge_sh + (size_t)e1c * 4);
    const float sh_s0 = s40.x, sh_s1 = s41.x;

    const float* nf0 = node_ft + (size_t)snd0 * 40;
    const float* nf1 = node_ft + (size_t)snd1 * 40;

    __syncthreads();

    float hv0[32], hv1[32];
    {
        float es[16];
        const float4* a0 = (const float4*)(edge_scalars + (size_t)e0c * 16);
#pragma unroll
        for (int t = 0; t < 4; ++t) {
            const float4 v = a0[t];
            es[4*t+0]=v.x; es[4*t+1]=v.y; es[4*t+2]=v.z; es[4*t+3]=v.w;
        }
#pragma unroll
        for (int j = 0; j < 32; ++j) {
            float a = 0.f;
#pragma unroll
            for (int t = 0; t < 16; ++t) a += es[t] * fcv_w1[t*32 + j];
            hv0[j] = silu_f(a * 0.25f);
        }
        const float4* a1 = (const float4*)(edge_scalars + (size_t)e1c * 16);
#pragma unroll
        for (int t = 0; t < 4; ++t) {
            const float4 v = a1[t];
            es[4*t+0]=v.x; es[4*t+1]=v.y; es[4*t+2]=v.z; es[4*t+3]=v.w;
        }
#pragma unroll
        for (int j = 0; j < 32; ++j) {
            float a = 0.f;
#pragma unroll
            for (int t = 0; t < 16; ++t) a += es[t] * fcv_w1[t*32 + j];
            hv1[j] = silu_f(a * 0.25f);
        }
    }

    const uint4* g = sa4 + p * 385;
    float A0[16] = {}, A1[16] = {};

    // ---- v1 path (xs*shs, i = 4p+k) ----
#pragma unroll 1
    for (int k = 0; k < 4; ++k) {
        const float x0 = nf0[4*p + k] * sh_s0;
        const float x1 = nf1[4*p + k] * sh_s1;
        const uint4* gk = g + k * 64;
#pragma unroll
        for (int j = 0; j < 32; ++j) {
            const uint4 a = gk[2*j];
            const uint4 b = gk[2*j + 1];
            const float t0 = x0 * hv0[j], t1 = x1 * hv1[j];
            float wv[16]; up8(a, wv); up8(b, wv + 8);
#pragma unroll
            for (int o = 0; o < 16; ++o) { A0[o] += t0*wv[o]; A1[o] += t1*wv[o]; }
        }
    }

    // ---- v2 path (xv.shv, i = 2p+k), accumulate into the same outputs ----
    const float c3 = 0.57735026918962576f;
#pragma unroll 1
    for (int k = 0; k < 2; ++k) {
        const int i = 2*p + k;
        const float p0 = (nf0[16+3*i]*s40.y + nf0[17+3*i]*s40.z + nf0[18+3*i]*s40.w) * c3;
        const float p1 = (nf1[16+3*i]*s41.y + nf1[17+3*i]*s41.z + nf1[18+3*i]*s41.w) * c3;
        const uint4* gk = g + 256 + k * 64;
#pragma unroll
        for (int j = 0; j < 32; ++j) {
            const uint4 a = gk[2*j];
            const uint4 b = gk[2*j + 1];
            const float t0 = p0 * hv0[j], t1 = p1 * hv1[j];
            float wv[16]; up8(a, wv); up8(b, wv + 8);
#pragma unroll
            for (int o = 0; o < 16; ++o) { A0[o] += t0*wv[o]; A1[o] += t1*wv[o]; }
        }
    }

#pragma unroll
    for (int o = 0; o < 16; ++o) { A0[o] = wred4(A0[o]); A1[o] = wred4(A1[o]); }

    if (p == 0) {
        const float cs = 0.03608439182435161f;   // (1/sqrt32)*(1/sqrt24)
        if (val0) {
            const float sa0 = sabuf[e0];
            const int pos0 = posbuf[e0];
            float4* vp = (float4*)(vbuf + (size_t)pos0 * 40);
#pragma unroll
            for (int t = 0; t < 4; ++t) {
                float4 r;
                r.x = sa0 * A0[4*t+0] * cs; r.y = sa0 * A0[4*t+1] * cs;
                r.z = sa0 * A0[4*t+2] * cs; r.w = sa0 * A0[4*t+3] * cs;
                vp[t] = r;
            }
        }
        if (val1) {
            const float sa1 = sabuf[e1];
            const int pos1 = posbuf[e1];
            float4* vp = (float4*)(vbuf + (size_t)pos1 * 40);
#pragma unroll
            for (int t = 0; t < 4; ++t) {
                float4 r;
                r.x = sa1 * A1[4*t+0] * cs; r.y = sa1 * A1[4*t+1] * cs;
                r.z = sa1 * A1[4*t+2] * cs; r.w = sa1 * A1[4*t+3] * cs;
                vp[t] = r;
            }
        }
    }
}

// ===================== edge_v_b: V vector outputs (cols [384,640)) =====================
// LDS: 4 x 257 uint4 = 16448 B (stride 4112 B, %128==16 -> conflict-free).
// Chunk map: [0,128)=w3 (k*32+j), [128,192)=w4 (k*32+j), [192,256)=w5 (k*32+j).
__global__ __launch_bounds__(BS) void edge_v_b(
    const float* __restrict__ node_ft,
    const int*   __restrict__ ei,
    const float* __restrict__ edge_sh,
    const float* __restrict__ edge_scalars,
    const float* __restrict__ fcv_w1,
    const float* __restrict__ fcv_w2,
    const float* __restrict__ sabuf,
    const int*   __restrict__ posbuf,
    float* __restrict__ vbuf,               // [E,40]
    const int* __restrict__ flag,
    int E)
{
    __shared__ uint4 sb4[4 * 257];          // 16448 B

    const int tid = threadIdx.x;
    for (int idx = tid; idx < 4 * 256; idx += BS) {
        const int p = idx >> 8;
        const int local = idx & 255;
        int j, c0;
        if (local < 128) {                           // w3: i = 4p+k
            const int k = local >> 5; j = local & 31; c0 = 384 + (4*p + k) * 8;
        } else if (local < 192) {                    // w4: i = 2p+k
            const int l = local - 128; const int k = l >> 5; j = l & 31;
            c0 = 512 + (2*p + k) * 8;
        } else {                                     // w5: i = 2p+k
            const int l = local - 192; const int k = l >> 5; j = l & 31;
            c0 = 576 + (2*p + k) * 8;
        }
        const float* src = fcv_w2 + j * 640 + c0;
        sb4[p * 257 + local] = make_uint4(
            pk2(src[0], src[1]), pk2(src[2], src[3]),
            pk2(src[4], src[5]), pk2(src[6], src[7]));
    }

    const int lane = tid & 63;
    const int p = lane >> 4;
    const int q = lane & 15;
    const int w = tid >> 6;
    const int e0 = blockIdx.x * EPB + w * 32 + 2 * q;
    const int e1 = e0 + 1;
    const bool val0 = (e0 < E), val1 = (e1 < E);
    const int e0c = val0 ? e0 : (E - 1);
    const int e1c = val1 ? e1 : (E - 1);

    const int is64 = *flag;
    const int snd0 = is64 ? ei[2*e0c] : ei[e0c];
    const int snd1 = is64 ? ei[2*e1c] : ei[e1c];

    const float4 s40 = *(const float4*)(edge_sh + (size_t)e0c * 4);
    const float4 s41 = *(const float4*)(edge_sh + (size_t)e1c * 4);
    const float sh_s0 = s40.x, sh_s1 = s41.x;
    const float sh_v0[3] = {s40.y, s40.z, s40.w};
    const float sh_v1[3] = {s41.y, s41.z, s41.w};

    const float* nf0 = node_ft + (size_t)snd0 * 40;
    const float* nf1 = node_ft + (size_t)snd1 * 40;

    __syncthreads();

    float hv0[32], hv1[32];
    {
        float es[16];
        const float4* a0 = (const float4*)(edge_scalars + (size_t)e0c * 16);
#pragma unroll
        for (int t = 0; t < 4; ++t) {
            const float4 v = a0[t];
            es[4*t+0]=v.x; es[4*t+1]=v.y; es[4*t+2]=v.z; es[4*t+3]=v.w;
        }
#pragma unroll
        for (int j = 0; j < 32; ++j) {
            float a = 0.f;
#pragma unroll
            for (int t = 0; t < 16; ++t) a += es[t] * fcv_w1[t*32 + j];
            hv0[j] = silu_f(a * 0.25f);
        }
        const float4* a1 = (const float4*)(edge_scalars + (size_t)e1c * 16);
#pragma unroll
        for (int t = 0; t < 4; ++t) {
            const float4 v = a1[t];
            es[4*t+0]=v.x; es[4*t+1]=v.y; es[4*t+2]=v.z; es[4*t+3]=v.w;
        }
#pragma unroll
        for (int j = 0; j < 32; ++j) {
            float a = 0.f;
#pragma unroll
            for (int t = 0; t < 16; ++t) a += es[t] * fcv_w1[t*32 + j];
            hv1[j] = silu_f(a * 0.25f);
        }
    }

    const uint4* g = sb4 + p * 257;

    // ---- v3 path (xs (x) shv; shv applied after reduction) ----
    float T30[8] = {}, T31[8] = {};
#pragma unroll 1
    for (int k = 0; k < 4; ++k) {
        const float x0 = nf0[4*p + k];
        const float x1 = nf1[4*p + k];
        const uint4* gk = g + k * 32;
#pragma unroll
        for (int j = 0; j < 32; ++j) {
            const uint4 a = gk[j];
            const float t0 = x0 * hv0[j], t1 = x1 * hv1[j];
            float wv[8]; up8(a, wv);
#pragma unroll
            for (int o = 0; o < 8; ++o) { T30[o] += t0*wv[o]; T31[o] += t1*wv[o]; }
        }
    }

    // ---- v4/v5 paths (i = 2p+k); shs & cross folded per-k ----
    float R0[24] = {}, R1[24] = {};
    const float c7 = 0.70710678118654752f;
#pragma unroll 1
    for (int k = 0; k < 2; ++k) {
        const int i = 2*p + k;
        const float x00 = nf0[16 + 3*i], x01 = nf0[17 + 3*i], x02 = nf0[18 + 3*i];
        const float x10 = nf1[16 + 3*i], x11 = nf1[17 + 3*i], x12 = nf1[18 + 3*i];
        float W40[8] = {}, W41[8] = {}, W50[8] = {}, W51[8] = {};
        const uint4* g4 = g + 128 + k * 32;
        const uint4* g5 = g + 192 + k * 32;
#pragma unroll
        for (int j = 0; j < 32; ++j) {
            const uint4 a = g4[j];
            const uint4 b = g5[j];
            const float h0 = hv0[j], h1 = hv1[j];
            float wv[8], wu[8]; up8(a, wv); up8(b, wu);
#pragma unroll
            for (int o = 0; o < 8; ++o) {
                W40[o] += h0*wv[o]; W41[o] += h1*wv[o];
                W50[o] += h0*wu[o]; W51[o] += h1*wu[o];
            }
        }
        const float s00 = sh_s0*x00, s01 = sh_s0*x01, s02 = sh_s0*x02;
        const float s10 = sh_s1*x10, s11 = sh_s1*x11, s12 = sh_s1*x12;
        const float cx00 = c7*(x01*sh_v0[2] - x02*sh_v0[1]);
        const float cx01 = c7*(x02*sh_v0[0] - x00*sh_v0[2]);
        const float cx02 = c7*(x00*sh_v0[1] - x01*sh_v0[0]);
        const float cx10 = c7*(x11*sh_v1[2] - x12*sh_v1[1]);
        const float cx11 = c7*(x12*sh_v1[0] - x10*sh_v1[2]);
        const float cx12 = c7*(x10*sh_v1[1] - x11*sh_v1[0]);
#pragma unroll
        for (int o = 0; o < 8; ++o) {
            R0[o*3+0] += s00*W40[o] + cx00*W50[o];
            R0[o*3+1] += s01*W40[o] + cx01*W50[o];
            R0[o*3+2] += s02*W40[o] + cx02*W50[o];
            R1[o*3+0] += s10*W41[o] + cx10*W51[o];
            R1[o*3+1] += s11*W41[o] + cx11*W51[o];
            R1[o*3+2] += s12*W41[o] + cx12*W51[o];
        }
    }

#pragma unroll
    for (int o = 0; o < 8; ++o) { T30[o] = wred4(T30[o]); T31[o] = wred4(T31[o]); }
#pragma unroll
    for (int o = 0; o < 24; ++o) { R0[o] = wred4(R0[o]); R1[o] = wred4(R1[o]); }

    if (p == 0) {
        const float sc = 0.03125f;               // (1/sqrt32)*(1/sqrt32)
        if (val0) {
            const float sa0 = sabuf[e0];
            const int pos0 = posbuf[e0];
            float row[24];
#pragma unroll
            for (int o = 0; o < 8; ++o)
#pragma unroll
                for (int c = 0; c < 3; ++c)
                    row[o*3+c] = sa0 * (T30[o]*sh_v0[c] + R0[o*3+c]) * sc;
            float4* vp = (float4*)(vbuf + (size_t)pos0 * 40 + 16);
#pragma unroll
            for (int t = 0; t < 6; ++t) {
                float4 r; r.x = row[4*t+0]; r.y = row[4*t+1]; r.z = row[4*t+2]; r.w = row[4*t+3];
                vp[t] = r;
            }
        }
        if (val1) {
            const float sa1 = sabuf[e1];
            const int pos1 = posbuf[e1];
            float row[24];
#pragma unroll
            for (int o = 0; o < 8; ++o)
#pragma unroll
                for (int c = 0; c < 3; ++c)
                    row[o*3+c] = sa1 * (T31[o]*sh_v1[c] + R1[o*3+c]) * sc;
            float4* vp = (float4*)(vbuf + (size_t)pos1 * 40 + 16);
#pragma unroll
            for (int t = 0; t < 6; ++t) {
                float4 r; r.x = row[4*t+0]; r.y = row[4*t+1]; r.z = row[4*t+2]; r.w = row[4*t+3];
                vp[t] = r;
            }
        }
    }
}

__global__ __launch_bounds__(256) void node_reduce(
    const int*   __restrict__ start,
    const float* __restrict__ exbuf,
    const float* __restrict__ vbuf,
    float* __restrict__ out, int N)
{
    const int wave = threadIdx.x >> 6;
    const int lane = threadIdx.x & 63;
    const int n = blockIdx.x * 4 + wave;
    if (n >= N) return;
    const int r0 = start[n], r1 = start[n + 1];
    float z = 0.f, comp = 0.f;
    for (int r = r0; r < r1; ++r) {
        z += exbuf[r];
        if (lane < 40) comp += vbuf[(size_t)r * 40 + lane];
    }
    if (lane < 40)
        out[(size_t)n * 40 + lane] = (z > 0.f) ? comp * rsqrtf(z) : 0.f;
}

extern "C" void kernel_launch(void* const* d_in, const int* in_sizes, int n_in,
                              void* d_out, int out_size, void* d_ws, size_t ws_size,
                              hipStream_t stream) {
    const float* node_ft      = (const float*)d_in[0];
    const int*   edge_index   = (const int*)  d_in[1];
    const float* edge_sh      = (const float*)d_in[2];
    const float* edge_scalars = (const float*)d_in[3];
    const float* w_q_s        = (const float*)d_in[4];
    const float* w_q_v        = (const float*)d_in[5];
    const float* fck_w1       = (const float*)d_in[6];
    const float* fck_w2       = (const float*)d_in[7];
    const float* fcv_w1       = (const float*)d_in[8];
    const float* fcv_w2       = (const float*)d_in[9];
    const float* wdot_s       = (const float*)d_in[10];
    const float* wdot_v       = (const float*)d_in[11];

    const int N = in_sizes[0] / 40;
    const int E = in_sizes[2] / 4;

    float* ws    = (float*)d_ws;
    float* qd    = ws;                               // N*20
    int*   cnt   = (int*)(ws + (size_t)N * 20);      // N
    int*   start = cnt + N;                          // N+1
    int*   curs  = start + N + 1;                    // N
    int*   flg   = curs + N;                         // 1
    size_t off   = (size_t)N * 20 + N + (N + 1) + N + 1;
    off = (off + 3) & ~(size_t)3;                    // 16B align
    float* exbuf  = ws + off;                        // E
    float* sabuf  = exbuf + E;                       // E
    int*   posbuf = (int*)(sabuf + E);               // E
    float* vbuf   = (float*)(posbuf + E);            // E*40 (E%4==0 -> aligned)

    float* out = (float*)d_out;

    const int EB = (E + EPB - 1) / EPB;

    hipLaunchKernelGGL(node_pre, dim3((N + 255) / 256), dim3(256), 0, stream,
                       node_ft, edge_index, w_q_s, w_q_v, wdot_s, wdot_v,
                       qd, cnt, flg, N, E);
    hipLaunchKernelGGL(count_edges, dim3((E + 255) / 256), dim3(256), 0, stream,
                       edge_index, cnt, flg, E);
    hipLaunchKernelGGL(scan_kernel, dim3(1), dim3(1024), 0, stream,
                       cnt, start, curs, N);
    hipLaunchKernelGGL(edge_k, dim3(EB), dim3(BS), 0, stream,
                       node_ft, edge_index, edge_sh, edge_scalars,
                       fck_w1, fck_w2, qd, curs, exbuf, sabuf, posbuf, flg, N, E);
    hipLaunchKernelGGL(edge_v_a, dim3(EB), dim3(BS), 0, stream,
                       node_ft, edge_index, edge_sh, edge_scalars,
                       fcv_w1, fcv_w2, sabuf, posbuf, vbuf, flg, E);
    hipLaunchKernelGGL(edge_v_b, dim3(EB), dim3(BS), 0, stream,
                       node_ft, edge_index, edge_sh, edge_scalars,
                       fcv_w1, fcv_w2, sabuf, posbuf, vbuf, flg, E);
    hipLaunchKernelGGL(node_reduce, dim3((N + 3) / 4), dim3(256), 0, stream,
                       start, exbuf, vbuf, out, N);
}